// Round 7
// baseline (304.190 us; speedup 1.0000x reference)
//
#include <hip/hip_runtime.h>
#include <hip/hip_bf16.h>

// Problem constants
#define BB   4
#define FF   9
#define MPP  100
#define PP   12000
#define CC   64
#define NYY  400
#define NXO  4
#define NPIL (BB * PP)              // 48000
#define NWIN (BB * NYY * NXO)       // 6400 pooling windows

// ws layout (byte offsets)
#define WS_CNT    0                        // 6400 * 4  (window occupancy counts)
#define WS_BIAS1  (NWIN * 4)               // 64 fp32
#define WS_BIAS2  (WS_BIAS1 + 256)         // 64 fp32
#define WS_W1PB   (WS_BIAS2 + 256)         // 64x16 bf16 (s1-folded, k-slot mapped)
#define WS_W2PB   (WS_W1PB + 2048)         // 64x64 bf16 (s2-folded)
#define WS_BINS   (WS_W2PB + 8192)         // 6400*100 u16 pillar ids
#define WS_FEAT2  (WS_BINS + 1280000)      // 48000*64 bf16 (16B-aligned)

typedef __attribute__((ext_vector_type(8)))  short short8;   // 8 bf16 = 4 VGPRs
typedef __attribute__((ext_vector_type(16))) float float16;  // MFMA 32x32 acc

__device__ __forceinline__ short f2bf(float v) {
    __hip_bfloat16 h = __float2bfloat16(v);
    short s; __builtin_memcpy(&s, &h, 2); return s;
}
__device__ __forceinline__ float bf2f(unsigned short u) {
    return __int_as_float(((int)u) << 16);
}

// k-slot map for stage1 (must match pillar_kernel's B build):
//   s in [0,4)  -> f = s        (loaded by half0)
//   s in [8,13) -> f = s - 4    (loaded by half1)
__global__ void prep_kernel(const float* __restrict__ w1, const float* __restrict__ b1,
                            const float* __restrict__ g1, const float* __restrict__ be1,
                            const float* __restrict__ m1, const float* __restrict__ v1,
                            const float* __restrict__ w2, const float* __restrict__ b2,
                            const float* __restrict__ g2, const float* __restrict__ be2,
                            const float* __restrict__ m2, const float* __restrict__ v2,
                            char* __restrict__ ws)
{
    float* bias1 = (float*)(ws + WS_BIAS1);
    float* bias2 = (float*)(ws + WS_BIAS2);
    short* w1pb  = (short*)(ws + WS_W1PB);
    short* w2pb  = (short*)(ws + WS_W2PB);
    const int t = threadIdx.x;   // 256
    if (t < 64) {
        const float s1 = g1[t] * rsqrtf(v1[t] + 1e-3f);
        bias1[t] = s1 * b1[t] + (be1[t] - m1[t] * s1);
        #pragma unroll
        for (int s = 0; s < 16; ++s) {
            const int f = (s < 4) ? s : ((s >= 8 && s < 13) ? s - 4 : -1);
            w1pb[t * 16 + s] = (f >= 0) ? f2bf(s1 * w1[t * 9 + f]) : (short)0;
        }
        const float s2 = g2[t] * rsqrtf(v2[t] + 1e-3f);
        bias2[t] = s2 * b2[t] + (be2[t] - m2[t] * s2);
    }
    for (int i = t; i < CC * CC; i += 256) {
        const int d = i >> 6;
        const float s2 = g2[d] * rsqrtf(v2[d] + 1e-3f);
        w2pb[i] = f2bf(s2 * w2[i]);
    }
}

#define LOAD5(dst, ptr) do { \
    dst##0 = (ptr)[0]; dst##1 = (ptr)[FS]; dst##2 = (ptr)[2 * FS]; \
    dst##3 = (ptr)[3 * FS]; dst##4 = (ptr)[4 * FS]; } while (0)

// Block = 256 threads (4 waves), 32 pillars. Wave wv owns (ch-tile ct = wv&1,
// mp-half mh = wv>>1): ONE float16 accumulator. Inner loop processes 2 points
// per iteration (2 MFMA + 16 v_max3) with a 2-group-deep software pipeline
// (20 outstanding loads/wave) to hide HBM latency.
// Cross-wave merge: plain stores into red[2][64][32] (wave-exclusive regions).
// Stage2 (waves 0-1): K=64 MFMA chain -> relu -> s2f (overlays red) -> dense
// coalesced bf16 feat2 store. Binning: 1 atomicAdd per pillar.
__global__ __launch_bounds__(256, 5) void pillar_kernel(
    const float* __restrict__ x, const int* __restrict__ coords,
    char* __restrict__ ws, int* __restrict__ cnt)
{
    __shared__ char  arena[16384];        // red fp32[2][64][32] THEN s2f fp32[32][66]
    __shared__ short featbT[32 * 72];     // bf16 feat [p][c], stride 72 (16B-aligned)

    float* red = (float*)arena;
    float* s2f = (float*)arena;

    const float* bias1 = (const float*)(ws + WS_BIAS1);
    const float* bias2 = (const float*)(ws + WS_BIAS2);
    const short* w1pb  = (const short*)(ws + WS_W1PB);
    const short* w2pb  = (const short*)(ws + WS_W2PB);
    unsigned short* bins  = (unsigned short*)(ws + WS_BINS);
    short*          feat2 = (short*)(ws + WS_FEAT2);

    const int t    = threadIdx.x;
    const int lane = t & 63;
    const int wv   = t >> 6;          // 0..3
    const int ct   = wv & 1;          // channel tile (32 ch)
    const int mh   = wv >> 1;         // mp half (50 points)
    const int half = lane >> 5;       // k-group
    const int pcol = lane & 31;       // pillar column (n) / A row (m)
    const int v0   = blockIdx.x * 32; // never straddles a batch (12000 % 32 == 0)
    const int b    = v0 / PP;
    const int p0   = v0 - b * PP;

    // binning: 1 atomicAdd per pillar (48k total across grid)
    if (t < 32) {
        const int* c4 = coords + (size_t)(v0 + t) * 4;
        const int w = (c4[0] * NYY + c4[2]) * NXO + c4[3] / 100;
        const int slot = atomicAdd(&cnt[w], 1);
        bins[w * 100 + slot] = (unsigned short)(v0 + t);
    }

    // A fragment: w1' row (k-slot mapped) for channel ct*32 + pcol
    const short8 a0 = *(const short8*)(w1pb + (ct * 32 + pcol) * 16 + half * 8);

    float16 vmx;
    #pragma unroll
    for (int r = 0; r < 16; ++r) vmx[r] = -3.0e38f;

    // x[b][f][mp][p]; this lane's f-base: half0 -> f=0.., half1 -> f=4..
    const size_t FS = (size_t)MPP * PP;    // feature stride (floats)
    const float* q = x + (size_t)b * FF * FS
                       + (size_t)(mh * 50) * PP
                       + (size_t)half * 4 * FS
                       + p0 + pcol;

    // software pipeline: 25 groups of 2 points, depth 2 (20 loads in flight)
    float a_0, a_1, a_2, a_3, a_4, b_0, b_1, b_2, b_3, b_4;   // group i
    float c_0, c_1, c_2, c_3, c_4, d_0, d_1, d_2, d_3, d_4;   // group i+1
    LOAD5(a_, q); q += PP; LOAD5(b_, q); q += PP;             // g0
    LOAD5(c_, q); q += PP; LOAD5(d_, q); q += PP;             // g1

    for (int it = 0; it < 23; ++it) {
        float n0_0, n0_1, n0_2, n0_3, n0_4, n1_0, n1_1, n1_2, n1_3, n1_4;
        LOAD5(n0_, q); q += PP; LOAD5(n1_, q); q += PP;       // g(it+2)
        short8 bfA = (short8)0, bfB = (short8)0;
        bfA[0] = f2bf(a_0); bfA[1] = f2bf(a_1); bfA[2] = f2bf(a_2); bfA[3] = f2bf(a_3);
        bfA[4] = half ? f2bf(a_4) : (short)0;   // half0's 5th load = f4 dup, discarded
        bfB[0] = f2bf(b_0); bfB[1] = f2bf(b_1); bfB[2] = f2bf(b_2); bfB[3] = f2bf(b_3);
        bfB[4] = half ? f2bf(b_4) : (short)0;
        const float16 z0 = __builtin_amdgcn_mfma_f32_32x32x16_bf16(a0, bfA, (float16)0.f, 0, 0, 0);
        const float16 z1 = __builtin_amdgcn_mfma_f32_32x32x16_bf16(a0, bfB, (float16)0.f, 0, 0, 0);
        #pragma unroll
        for (int r = 0; r < 16; ++r)
            vmx[r] = fmaxf(fmaxf(vmx[r], z0[r]), z1[r]);      // v_max3_f32
        a_0 = c_0; a_1 = c_1; a_2 = c_2; a_3 = c_3; a_4 = c_4;
        b_0 = d_0; b_1 = d_1; b_2 = d_2; b_3 = d_3; b_4 = d_4;
        c_0 = n0_0; c_1 = n0_1; c_2 = n0_2; c_3 = n0_3; c_4 = n0_4;
        d_0 = n1_0; d_1 = n1_1; d_2 = n1_2; d_3 = n1_3; d_4 = n1_4;
    }
    // epilogue: groups 23, 24 (in a_/b_ and c_/d_)
    #pragma unroll
    for (int e = 0; e < 2; ++e) {
        short8 bfA = (short8)0, bfB = (short8)0;
        if (e == 0) {
            bfA[0] = f2bf(a_0); bfA[1] = f2bf(a_1); bfA[2] = f2bf(a_2); bfA[3] = f2bf(a_3);
            bfA[4] = half ? f2bf(a_4) : (short)0;
            bfB[0] = f2bf(b_0); bfB[1] = f2bf(b_1); bfB[2] = f2bf(b_2); bfB[3] = f2bf(b_3);
            bfB[4] = half ? f2bf(b_4) : (short)0;
        } else {
            bfA[0] = f2bf(c_0); bfA[1] = f2bf(c_1); bfA[2] = f2bf(c_2); bfA[3] = f2bf(c_3);
            bfA[4] = half ? f2bf(c_4) : (short)0;
            bfB[0] = f2bf(d_0); bfB[1] = f2bf(d_1); bfB[2] = f2bf(d_2); bfB[3] = f2bf(d_3);
            bfB[4] = half ? f2bf(d_4) : (short)0;
        }
        const float16 z0 = __builtin_amdgcn_mfma_f32_32x32x16_bf16(a0, bfA, (float16)0.f, 0, 0, 0);
        const float16 z1 = __builtin_amdgcn_mfma_f32_32x32x16_bf16(a0, bfB, (float16)0.f, 0, 0, 0);
        #pragma unroll
        for (int r = 0; r < 16; ++r)
            vmx[r] = fmaxf(fmaxf(vmx[r], z0[r]), z1[r]);
    }

    // plain stores: wave-exclusive region red[mh][ct*32 + chl][pcol]
    // D layout: col=lane&31, row(chl)=(r&3)+8*(r>>2)+4*(lane>>5)
    #pragma unroll
    for (int r = 0; r < 16; ++r) {
        const int chl = (r & 3) + 8 * (r >> 2) + 4 * half;
        red[mh * 2048 + (ct * 32 + chl) * 32 + pcol] = vmx[r];
    }
    __syncthreads();

    // feat = relu(max over mp-halves + bias1) -> bf16, transposed [p][c]
    {
        const int p  = t & 31;
        const int cg = t >> 5;      // 0..7, 8 channels each
        #pragma unroll
        for (int j = 0; j < 8; ++j) {
            const int c = cg * 8 + j;
            const float m = fmaxf(red[c * 32 + p], red[2048 + c * 32 + p]);
            featbT[p * 72 + c] = f2bf(fmaxf(0.f, m + bias1[c]));
        }
    }
    __syncthreads();

    // Stage2 on waves 0-1: wave wv computes d = wv*32..+31, K=64 in 4 chunks.
    // s2f overlays red (red fully consumed above, barrier passed).
    if (wv < 2) {
        const short* wrow = w2pb + (wv * 32 + pcol) * 64 + half * 8;
        const short8 wa0 = *(const short8*)(wrow +  0);
        const short8 wa1 = *(const short8*)(wrow + 16);
        const short8 wa2 = *(const short8*)(wrow + 32);
        const short8 wa3 = *(const short8*)(wrow + 48);
        const short* frow = &featbT[pcol * 72 + half * 8];
        const short8 fb0 = *(const short8*)(frow +  0);
        const short8 fb1 = *(const short8*)(frow + 16);
        const short8 fb2 = *(const short8*)(frow + 32);
        const short8 fb3 = *(const short8*)(frow + 48);

        float16 acc = (float16)0.f;
        acc = __builtin_amdgcn_mfma_f32_32x32x16_bf16(wa0, fb0, acc, 0, 0, 0);
        acc = __builtin_amdgcn_mfma_f32_32x32x16_bf16(wa1, fb1, acc, 0, 0, 0);
        acc = __builtin_amdgcn_mfma_f32_32x32x16_bf16(wa2, fb2, acc, 0, 0, 0);
        acc = __builtin_amdgcn_mfma_f32_32x32x16_bf16(wa3, fb3, acc, 0, 0, 0);

        #pragma unroll
        for (int r = 0; r < 16; ++r) {
            const int d = wv * 32 + (r & 3) + 8 * (r >> 2) + 4 * half;
            s2f[pcol * 66 + d] = fmaxf(0.f, acc[r] + bias2[d]);
        }
    }
    __syncthreads();

    // dense coalesced bf16 store: feat2[(v0+p)*64 + d], 8 values/thread (16 B)
    {
        const int p  = t >> 3;
        const int d0 = (t & 7) * 8;
        short8 o;
        #pragma unroll
        for (int j = 0; j < 8; ++j) o[j] = f2bf(s2f[p * 66 + d0 + j]);
        *(short8*)(feat2 + (size_t)(v0 + p) * 64 + d0) = o;
    }
}

// One block = 64 windows; thread t: window wl=t&63, d-group dg=t>>6 (16 d's each).
// out[b,d,y,xo] = max over binned pillars of feat2[pid][d], plus zval=relu(bias2[d])
// unless the 100-wide window is fully occupied.
__global__ __launch_bounds__(256) void gather_kernel(
    const char* __restrict__ ws, const int* __restrict__ cnt,
    float* __restrict__ out)
{
    const float* bias2 = (const float*)(ws + WS_BIAS2);
    const unsigned short* bins  = (const unsigned short*)(ws + WS_BINS);
    const unsigned short* feat2 = (const unsigned short*)(ws + WS_FEAT2);

    const int t  = threadIdx.x;
    const int wl = t & 63;
    const int dg = t >> 6;                    // 0..3
    const int w  = blockIdx.x * 64 + wl;      // < 6400
    const int k  = cnt[w];

    float m[16];
    #pragma unroll
    for (int j = 0; j < 16; ++j) {
        const float zv = fmaxf(0.f, bias2[dg * 16 + j]);
        m[j] = (k >= 100) ? 0.f : zv;         // post-ReLU vals >= 0, so 0 is safe
    }
    int i = 0;
    for (; i + 2 <= k; i += 2) {
        const int pidA = bins[w * 100 + i];
        const int pidB = bins[w * 100 + i + 1];
        const unsigned short* rowA = feat2 + (size_t)pidA * 64 + dg * 16;
        const unsigned short* rowB = feat2 + (size_t)pidB * 64 + dg * 16;
        #pragma unroll
        for (int j = 0; j < 16; ++j)
            m[j] = fmaxf(fmaxf(m[j], bf2f(rowA[j])), bf2f(rowB[j]));  // v_max3
    }
    if (i < k) {
        const int pid = bins[w * 100 + i];
        const unsigned short* row = feat2 + (size_t)pid * 64 + dg * 16;
        #pragma unroll
        for (int j = 0; j < 16; ++j) m[j] = fmaxf(m[j], bf2f(row[j]));
    }

    const int b   = w / (NYY * NXO);
    const int rem = w - b * (NYY * NXO);
    const int y   = rem >> 2;
    const int xo  = rem & 3;
    #pragma unroll
    for (int j = 0; j < 16; ++j) {
        const int d = dg * 16 + j;
        out[(((size_t)b * CC + d) * NYY + y) * NXO + xo] = m[j];
    }
}

extern "C" void kernel_launch(void* const* d_in, const int* in_sizes, int n_in,
                              void* d_out, int out_size, void* d_ws, size_t ws_size,
                              hipStream_t stream) {
    const float* x   = (const float*)d_in[0];
    const int*   cds = (const int*)d_in[1];
    const float* w1  = (const float*)d_in[2];
    const float* b1  = (const float*)d_in[3];
    const float* g1  = (const float*)d_in[4];
    const float* be1 = (const float*)d_in[5];
    const float* m1  = (const float*)d_in[6];
    const float* v1  = (const float*)d_in[7];
    const float* w2  = (const float*)d_in[8];
    const float* b2  = (const float*)d_in[9];
    const float* g2  = (const float*)d_in[10];
    const float* be2 = (const float*)d_in[11];
    const float* m2  = (const float*)d_in[12];
    const float* v2  = (const float*)d_in[13];

    char* ws = (char*)d_ws;
    int*  cnt = (int*)(ws + WS_CNT);

    // zero only the 25.6 KB window counters (ws re-poisoned 0xAA each launch)
    hipMemsetAsync(cnt, 0, (size_t)NWIN * 4, stream);

    prep_kernel<<<1, 256, 0, stream>>>(w1, b1, g1, be1, m1, v1,
                                       w2, b2, g2, be2, m2, v2, ws);

    pillar_kernel<<<NPIL / 32, 256, 0, stream>>>(x, cds, ws, cnt);

    gather_kernel<<<NWIN / 64, 256, 0, stream>>>(ws, cnt, (float*)d_out);
}

// Round 8
// 276.826 us; speedup vs baseline: 1.0988x; 1.0988x over previous
//
#include <hip/hip_runtime.h>
#include <hip/hip_bf16.h>

// Problem constants
#define BB   4
#define FF   9
#define MPP  100
#define PP   12000
#define CC   64
#define NYY  400
#define NXO  4
#define NPIL (BB * PP)              // 48000
#define NWIN (BB * NYY * NXO)       // 6400 pooling windows

// ws layout (byte offsets)
#define WS_CNT    0                        // 6400 * 4  (window occupancy counts)
#define WS_BIAS1  (NWIN * 4)               // 64 fp32
#define WS_BIAS2  (WS_BIAS1 + 256)         // 64 fp32
#define WS_W1PB   (WS_BIAS2 + 256)         // 64x16 bf16 (s1-folded, k-slot mapped)
#define WS_W2PB   (WS_W1PB + 2048)         // 64x64 bf16 (s2-folded)
#define WS_BINS   (WS_W2PB + 8192)         // 6400*100 u16 pillar ids
#define WS_FEAT2  (WS_BINS + 1280000)      // 48000*64 bf16 (16B-aligned)

typedef __attribute__((ext_vector_type(8)))  short short8;   // 8 bf16 = 4 VGPRs
typedef __attribute__((ext_vector_type(16))) float float16;  // MFMA 32x32 acc

__device__ __forceinline__ short f2bf(float v) {
    __hip_bfloat16 h = __float2bfloat16(v);
    short s; __builtin_memcpy(&s, &h, 2); return s;
}
__device__ __forceinline__ float bf2f(unsigned short u) {
    return __int_as_float(((int)u) << 16);
}
// order-preserving fp32 <-> int key (self-inverse XOR form)
__device__ __forceinline__ int fkey(float v) {
    int b = __float_as_int(v);
    return b >= 0 ? b : (b ^ 0x7fffffff);
}
__device__ __forceinline__ float kinv(int k) {
    return __int_as_float(k >= 0 ? k : (k ^ 0x7fffffff));
}

// k-slot map for stage1 (must match pillar_kernel's B build):
//   s in [0,4)  -> f = s        (loaded by half0)
//   s in [8,13) -> f = s - 4    (loaded by half1)
__global__ void prep_kernel(const float* __restrict__ w1, const float* __restrict__ b1,
                            const float* __restrict__ g1, const float* __restrict__ be1,
                            const float* __restrict__ m1, const float* __restrict__ v1,
                            const float* __restrict__ w2, const float* __restrict__ b2,
                            const float* __restrict__ g2, const float* __restrict__ be2,
                            const float* __restrict__ m2, const float* __restrict__ v2,
                            char* __restrict__ ws)
{
    float* bias1 = (float*)(ws + WS_BIAS1);
    float* bias2 = (float*)(ws + WS_BIAS2);
    short* w1pb  = (short*)(ws + WS_W1PB);
    short* w2pb  = (short*)(ws + WS_W2PB);
    const int t = threadIdx.x;   // 256
    if (t < 64) {
        const float s1 = g1[t] * rsqrtf(v1[t] + 1e-3f);
        bias1[t] = s1 * b1[t] + (be1[t] - m1[t] * s1);
        #pragma unroll
        for (int s = 0; s < 16; ++s) {
            const int f = (s < 4) ? s : ((s >= 8 && s < 13) ? s - 4 : -1);
            w1pb[t * 16 + s] = (f >= 0) ? f2bf(s1 * w1[t * 9 + f]) : (short)0;
        }
        const float s2 = g2[t] * rsqrtf(v2[t] + 1e-3f);
        bias2[t] = s2 * b2[t] + (be2[t] - m2[t] * s2);
    }
    for (int i = t; i < CC * CC; i += 256) {
        const int d = i >> 6;
        const float s2 = g2[d] * rsqrtf(v2[d] + 1e-3f);
        w2pb[i] = f2bf(s2 * w2[i]);
    }
}

// Non-temporal x loads: evict-first, don't trash L3 (which is full of dirty
// harness-poison lines whose forced writeback was serializing with our read).
#define LOAD5(dst, ptr) do { \
    dst##0 = __builtin_nontemporal_load((ptr)); \
    dst##1 = __builtin_nontemporal_load((ptr) + FS); \
    dst##2 = __builtin_nontemporal_load((ptr) + 2 * FS); \
    dst##3 = __builtin_nontemporal_load((ptr) + 3 * FS); \
    dst##4 = __builtin_nontemporal_load((ptr) + 4 * FS); } while (0)

#define BUILD_BF(bf, s_) do { \
    bf[0] = f2bf(s_##0); bf[1] = f2bf(s_##1); bf[2] = f2bf(s_##2); \
    bf[3] = f2bf(s_##3); bf[4] = half ? f2bf(s_##4) : (short)0; } while (0)

#define STEP2(sA, sB) do { \
    short8 bfA = (short8)0, bfB = (short8)0; \
    BUILD_BF(bfA, sA); BUILD_BF(bfB, sB); \
    const float16 z0A = __builtin_amdgcn_mfma_f32_32x32x16_bf16(af0, bfA, (float16)0.f, 0, 0, 0); \
    const float16 z1A = __builtin_amdgcn_mfma_f32_32x32x16_bf16(af1, bfA, (float16)0.f, 0, 0, 0); \
    const float16 z0B = __builtin_amdgcn_mfma_f32_32x32x16_bf16(af0, bfB, (float16)0.f, 0, 0, 0); \
    const float16 z1B = __builtin_amdgcn_mfma_f32_32x32x16_bf16(af1, bfB, (float16)0.f, 0, 0, 0); \
    _Pragma("unroll") \
    for (int r = 0; r < 16; ++r) { \
        vmx0[r] = fmaxf(fmaxf(vmx0[r], z0A[r]), z0B[r]); \
        vmx1[r] = fmaxf(fmaxf(vmx1[r], z1A[r]), z1B[r]); \
    } } while (0)

// Block = 256 threads (4 waves), 32 pillars. Wave wv owns mp-quarter
// [25wv, 25wv+25) and computes BOTH 32-channel tiles (x read exactly once
// block-wide -> NT loads safe). 2-point groups, depth-2 pipeline.
// Cross-wave merge: LDS atomicMax on order-int keys (red, 8 KB).
// Stage2 (waves 0-1): K=64 MFMA chain -> relu -> s2f (overlays red) -> dense
// coalesced bf16 feat2 store. Binning: 1 atomicAdd per pillar.
__global__ __launch_bounds__(256, 4) void pillar_kernel(
    const float* __restrict__ x, const int* __restrict__ coords,
    char* __restrict__ ws, int* __restrict__ cnt)
{
    __shared__ char  arena[8448];         // red int[64][32] THEN s2f fp32[32][66]
    __shared__ short featbT[32 * 72];     // bf16 feat [p][c], stride 72 (16B-aligned)

    int*   red = (int*)arena;
    float* s2f = (float*)arena;

    const float* bias1 = (const float*)(ws + WS_BIAS1);
    const float* bias2 = (const float*)(ws + WS_BIAS2);
    const short* w1pb  = (const short*)(ws + WS_W1PB);
    const short* w2pb  = (const short*)(ws + WS_W2PB);
    unsigned short* bins  = (unsigned short*)(ws + WS_BINS);
    short*          feat2 = (short*)(ws + WS_FEAT2);

    const int t    = threadIdx.x;
    const int lane = t & 63;
    const int wv   = t >> 6;          // 0..3 = mp quarter
    const int half = lane >> 5;       // k-group
    const int pcol = lane & 31;       // pillar column (n) / A row (m)
    const int v0   = blockIdx.x * 32; // never straddles a batch (12000 % 32 == 0)
    const int b    = v0 / PP;
    const int p0   = v0 - b * PP;

    // init reduction buffer (2048 ints, 8/thread), barrier before any atomicMax
    #pragma unroll
    for (int i = 0; i < 8; ++i) red[i * 256 + t] = (int)0x80000000;

    // binning: 1 atomicAdd per pillar (48k total across grid)
    if (t < 32) {
        const int* c4 = coords + (size_t)(v0 + t) * 4;
        const int w = (c4[0] * NYY + c4[2]) * NXO + c4[3] / 100;
        const int slot = atomicAdd(&cnt[w], 1);
        bins[w * 100 + slot] = (unsigned short)(v0 + t);
    }
    __syncthreads();

    // A fragments: w1' rows (k-slot mapped) for channels pcol and pcol+32
    const short8 af0 = *(const short8*)(w1pb + pcol * 16 + half * 8);
    const short8 af1 = *(const short8*)(w1pb + (pcol + 32) * 16 + half * 8);

    float16 vmx0, vmx1;
    #pragma unroll
    for (int r = 0; r < 16; ++r) { vmx0[r] = -3.0e38f; vmx1[r] = -3.0e38f; }

    // x[b][f][mp][p]; this lane's f-base: half0 -> f=0.., half1 -> f=4..
    const size_t FS = (size_t)MPP * PP;    // feature stride (floats)
    const float* q = x + (size_t)b * FF * FS
                       + (size_t)(wv * 25) * PP
                       + (size_t)half * 4 * FS
                       + p0 + pcol;

    // 25 points = 12 groups of 2 (depth-2 pipeline) + 1 tail point
    float a_0, a_1, a_2, a_3, a_4, b_0, b_1, b_2, b_3, b_4;   // group i
    float c_0, c_1, c_2, c_3, c_4, d_0, d_1, d_2, d_3, d_4;   // group i+1
    LOAD5(a_, q); LOAD5(b_, q + PP); q += 2 * PP;             // g0
    LOAD5(c_, q); LOAD5(d_, q + PP); q += 2 * PP;             // g1

    for (int it = 0; it < 10; ++it) {
        float n0_0, n0_1, n0_2, n0_3, n0_4, n1_0, n1_1, n1_2, n1_3, n1_4;
        LOAD5(n0_, q); LOAD5(n1_, q + PP); q += 2 * PP;       // g(it+2)
        STEP2(a_, b_);
        a_0 = c_0; a_1 = c_1; a_2 = c_2; a_3 = c_3; a_4 = c_4;
        b_0 = d_0; b_1 = d_1; b_2 = d_2; b_3 = d_3; b_4 = d_4;
        c_0 = n0_0; c_1 = n0_1; c_2 = n0_2; c_3 = n0_3; c_4 = n0_4;
        d_0 = n1_0; d_1 = n1_1; d_2 = n1_2; d_3 = n1_3; d_4 = n1_4;
    }
    STEP2(a_, b_);                                            // g10
    STEP2(c_, d_);                                            // g11
    {   // tail point 24
        LOAD5(a_, q);
        short8 bfA = (short8)0;
        BUILD_BF(bfA, a_);
        const float16 z0 = __builtin_amdgcn_mfma_f32_32x32x16_bf16(af0, bfA, (float16)0.f, 0, 0, 0);
        const float16 z1 = __builtin_amdgcn_mfma_f32_32x32x16_bf16(af1, bfA, (float16)0.f, 0, 0, 0);
        #pragma unroll
        for (int r = 0; r < 16; ++r) {
            vmx0[r] = fmaxf(vmx0[r], z0[r]);
            vmx1[r] = fmaxf(vmx1[r], z1[r]);
        }
    }

    // merge across 4 mp-quarter waves: LDS atomicMax on ordered-int keys
    // D layout: col=lane&31, row(chl)=(r&3)+8*(r>>2)+4*(lane>>5)
    #pragma unroll
    for (int r = 0; r < 16; ++r) {
        const int chl = (r & 3) + 8 * (r >> 2) + 4 * half;
        atomicMax(&red[chl * 32 + pcol],        fkey(vmx0[r]));
        atomicMax(&red[(chl + 32) * 32 + pcol], fkey(vmx1[r]));
    }
    __syncthreads();

    // feat = relu(max + bias1) -> bf16, transposed [p][c]
    {
        const int p  = t & 31;
        const int cg = t >> 5;      // 0..7, 8 channels each
        #pragma unroll
        for (int j = 0; j < 8; ++j) {
            const int c = cg * 8 + j;
            const float m = kinv(red[c * 32 + p]);
            featbT[p * 72 + c] = f2bf(fmaxf(0.f, m + bias1[c]));
        }
    }
    __syncthreads();

    // Stage2 on waves 0-1: wave wv computes d = wv*32..+31, K=64 in 4 chunks.
    // s2f overlays red (red fully consumed above, barrier passed).
    if (wv < 2) {
        const short* wrow = w2pb + (wv * 32 + pcol) * 64 + half * 8;
        const short8 wa0 = *(const short8*)(wrow +  0);
        const short8 wa1 = *(const short8*)(wrow + 16);
        const short8 wa2 = *(const short8*)(wrow + 32);
        const short8 wa3 = *(const short8*)(wrow + 48);
        const short* frow = &featbT[pcol * 72 + half * 8];
        const short8 fb0 = *(const short8*)(frow +  0);
        const short8 fb1 = *(const short8*)(frow + 16);
        const short8 fb2 = *(const short8*)(frow + 32);
        const short8 fb3 = *(const short8*)(frow + 48);

        float16 acc = (float16)0.f;
        acc = __builtin_amdgcn_mfma_f32_32x32x16_bf16(wa0, fb0, acc, 0, 0, 0);
        acc = __builtin_amdgcn_mfma_f32_32x32x16_bf16(wa1, fb1, acc, 0, 0, 0);
        acc = __builtin_amdgcn_mfma_f32_32x32x16_bf16(wa2, fb2, acc, 0, 0, 0);
        acc = __builtin_amdgcn_mfma_f32_32x32x16_bf16(wa3, fb3, acc, 0, 0, 0);

        #pragma unroll
        for (int r = 0; r < 16; ++r) {
            const int d = wv * 32 + (r & 3) + 8 * (r >> 2) + 4 * half;
            s2f[pcol * 66 + d] = fmaxf(0.f, acc[r] + bias2[d]);
        }
    }
    __syncthreads();

    // dense coalesced bf16 store: feat2[(v0+p)*64 + d], 8 values/thread (16 B)
    {
        const int p  = t >> 3;
        const int d0 = (t & 7) * 8;
        short8 o;
        #pragma unroll
        for (int j = 0; j < 8; ++j) o[j] = f2bf(s2f[p * 66 + d0 + j]);
        *(short8*)(feat2 + (size_t)(v0 + p) * 64 + d0) = o;
    }
}

// One block = 64 windows; thread t: window wl=t&63, d-group dg=t>>6 (16 d's each).
// out[b,d,y,xo] = max over binned pillars of feat2[pid][d], plus zval=relu(bias2[d])
// unless the 100-wide window is fully occupied.
__global__ __launch_bounds__(256) void gather_kernel(
    const char* __restrict__ ws, const int* __restrict__ cnt,
    float* __restrict__ out)
{
    const float* bias2 = (const float*)(ws + WS_BIAS2);
    const unsigned short* bins  = (const unsigned short*)(ws + WS_BINS);
    const unsigned short* feat2 = (const unsigned short*)(ws + WS_FEAT2);

    const int t  = threadIdx.x;
    const int wl = t & 63;
    const int dg = t >> 6;                    // 0..3
    const int w  = blockIdx.x * 64 + wl;      // < 6400
    const int k  = cnt[w];

    float m[16];
    #pragma unroll
    for (int j = 0; j < 16; ++j) {
        const float zv = fmaxf(0.f, bias2[dg * 16 + j]);
        m[j] = (k >= 100) ? 0.f : zv;         // post-ReLU vals >= 0, so 0 is safe
    }
    int i = 0;
    for (; i + 2 <= k; i += 2) {
        const int pidA = bins[w * 100 + i];
        const int pidB = bins[w * 100 + i + 1];
        const unsigned short* rowA = feat2 + (size_t)pidA * 64 + dg * 16;
        const unsigned short* rowB = feat2 + (size_t)pidB * 64 + dg * 16;
        #pragma unroll
        for (int j = 0; j < 16; ++j)
            m[j] = fmaxf(fmaxf(m[j], bf2f(rowA[j])), bf2f(rowB[j]));  // v_max3
    }
    if (i < k) {
        const int pid = bins[w * 100 + i];
        const unsigned short* row = feat2 + (size_t)pid * 64 + dg * 16;
        #pragma unroll
        for (int j = 0; j < 16; ++j) m[j] = fmaxf(m[j], bf2f(row[j]));
    }

    const int b   = w / (NYY * NXO);
    const int rem = w - b * (NYY * NXO);
    const int y   = rem >> 2;
    const int xo  = rem & 3;
    #pragma unroll
    for (int j = 0; j < 16; ++j) {
        const int d = dg * 16 + j;
        out[(((size_t)b * CC + d) * NYY + y) * NXO + xo] = m[j];
    }
}

extern "C" void kernel_launch(void* const* d_in, const int* in_sizes, int n_in,
                              void* d_out, int out_size, void* d_ws, size_t ws_size,
                              hipStream_t stream) {
    const float* x   = (const float*)d_in[0];
    const int*   cds = (const int*)d_in[1];
    const float* w1  = (const float*)d_in[2];
    const float* b1  = (const float*)d_in[3];
    const float* g1  = (const float*)d_in[4];
    const float* be1 = (const float*)d_in[5];
    const float* m1  = (const float*)d_in[6];
    const float* v1  = (const float*)d_in[7];
    const float* w2  = (const float*)d_in[8];
    const float* b2  = (const float*)d_in[9];
    const float* g2  = (const float*)d_in[10];
    const float* be2 = (const float*)d_in[11];
    const float* m2  = (const float*)d_in[12];
    const float* v2  = (const float*)d_in[13];

    char* ws = (char*)d_ws;
    int*  cnt = (int*)(ws + WS_CNT);

    // zero only the 25.6 KB window counters (ws re-poisoned 0xAA each launch)
    hipMemsetAsync(cnt, 0, (size_t)NWIN * 4, stream);

    prep_kernel<<<1, 256, 0, stream>>>(w1, b1, g1, be1, m1, v1,
                                       w2, b2, g2, be2, m2, v2, ws);

    pillar_kernel<<<NPIL / 32, 256, 0, stream>>>(x, cds, ws, cnt);

    gather_kernel<<<NWIN / 64, 256, 0, stream>>>(ws, cnt, (float*)d_out);
}